// Round 1
// baseline (961.167 us; speedup 1.0000x reference)
//
#include <hip/hip_runtime.h>
#include <hip/hip_bf16.h>

// Problem constants (baked from reference)
// SEQ_LENS = [1024, 768, 512, 896, 640, 384, 1024, 896], TOTAL=6144
// EMBED=768, HEADS=12, HEAD_DIM=64, FFN=3072
#define TOTAL 6144
#define EMBED 768
#define QKV3  2304
#define FFN   3072
#define NH    12
#define HD    64

typedef unsigned short u16;
typedef unsigned int u32;
typedef float f32x4 __attribute__((ext_vector_type(4)));
typedef __bf16 bf16x8 __attribute__((ext_vector_type(8)));

__device__ __constant__ int BOFF[9] = {0, 1024, 1792, 2304, 3200, 3840, 4224, 5248, 6144};

__device__ __forceinline__ float b2f(u16 h) {
    union { u32 u; float f; } v; v.u = ((u32)h) << 16; return v.f;
}
__device__ __forceinline__ u16 f2b(float f) {
    union { u32 u; float f; } v; v.f = f;
    u32 u = v.u + 0x7fffu + ((v.u >> 16) & 1u);
    return (u16)(u >> 16);
}

// ---------------- fp32 -> bf16 convert ----------------
__global__ void cvt_kernel(const float* __restrict__ in, u16* __restrict__ out, int n4) {
    int i = blockIdx.x * blockDim.x + threadIdx.x;
    if (i < n4) {
        float4 v = ((const float4*)in)[i];
        ushort4 o;
        o.x = f2b(v.x); o.y = f2b(v.y); o.z = f2b(v.z); o.w = f2b(v.w);
        ((ushort4*)out)[i] = o;
    }
}

// ---------------- LayerNorm (row of 768), bf16 output ----------------
__global__ __launch_bounds__(256) void ln_kernel(const float* __restrict__ x,
                                                 const float* __restrict__ g,
                                                 const float* __restrict__ b,
                                                 u16* __restrict__ out) {
    int row = blockIdx.x * 4 + (threadIdx.x >> 6);
    int lane = threadIdx.x & 63;
    const float* xr = x + (size_t)row * EMBED;
    float4 v[3];
    float s = 0.f, sq = 0.f;
#pragma unroll
    for (int c = 0; c < 3; ++c) {
        v[c] = *(const float4*)(xr + c * 256 + lane * 4);
        s += v[c].x + v[c].y + v[c].z + v[c].w;
        sq += v[c].x * v[c].x + v[c].y * v[c].y + v[c].z * v[c].z + v[c].w * v[c].w;
    }
#pragma unroll
    for (int o = 32; o; o >>= 1) {
        s += __shfl_xor(s, o);
        sq += __shfl_xor(sq, o);
    }
    float mu = s * (1.f / 768.f);
    float var = sq * (1.f / 768.f) - mu * mu;
    float rs = rsqrtf(var + 1e-5f);
    u16* orow = out + (size_t)row * EMBED;
#pragma unroll
    for (int c = 0; c < 3; ++c) {
        int col = c * 256 + lane * 4;
        float4 gg = *(const float4*)(g + col);
        float4 bb = *(const float4*)(b + col);
        ushort4 o;
        o.x = f2b((v[c].x - mu) * rs * gg.x + bb.x);
        o.y = f2b((v[c].y - mu) * rs * gg.y + bb.y);
        o.z = f2b((v[c].z - mu) * rs * gg.z + bb.z);
        o.w = f2b((v[c].w - mu) * rs * gg.w + bb.w);
        *(ushort4*)(orow + col) = o;
    }
}

// ---------------- GEMM: C[M,N] = A[M,K] @ B[N,K]^T + bias (+relu) (+res) ----------------
// 64x64 tile, 4 waves (2x2), BK=64, mfma_f32_16x16x32_bf16
template <int RELU, int RES, int OUTB, int OUTF>
__global__ __launch_bounds__(256) void gemm_bt(const u16* __restrict__ A,
                                               const u16* __restrict__ B,
                                               const float* __restrict__ bias,
                                               const float* __restrict__ res,
                                               u16* __restrict__ outb,
                                               float* __restrict__ outf,
                                               int M, int N, int K) {
    __shared__ u16 As[64][72];
    __shared__ u16 Bs[64][72];
    int t = threadIdx.x;
    int lane = t & 63, w = t >> 6;
    int wr = w >> 1, wc = w & 1;
    int m0 = blockIdx.y * 64, n0 = blockIdx.x * 64;

    f32x4 acc[2][2];
#pragma unroll
    for (int m = 0; m < 2; ++m)
#pragma unroll
        for (int n = 0; n < 2; ++n) acc[m][n] = (f32x4)0.f;

    for (int k0 = 0; k0 < K; k0 += 64) {
        __syncthreads();
#pragma unroll
        for (int l = 0; l < 2; ++l) {
            int idx = l * 256 + t;
            int row = idx >> 3, cg = idx & 7;
            *(uint4*)&As[row][cg * 8] = *(const uint4*)&A[(size_t)(m0 + row) * K + k0 + cg * 8];
            *(uint4*)&Bs[row][cg * 8] = *(const uint4*)&B[(size_t)(n0 + row) * K + k0 + cg * 8];
        }
        __syncthreads();
#pragma unroll
        for (int kk = 0; kk < 2; ++kk) {
            int kcol = kk * 32 + (lane >> 4) * 8;
            bf16x8 af[2], bf[2];
#pragma unroll
            for (int m = 0; m < 2; ++m)
                af[m] = *(const bf16x8*)&As[wr * 32 + m * 16 + (lane & 15)][kcol];
#pragma unroll
            for (int n = 0; n < 2; ++n)
                bf[n] = *(const bf16x8*)&Bs[wc * 32 + n * 16 + (lane & 15)][kcol];
#pragma unroll
            for (int m = 0; m < 2; ++m)
#pragma unroll
                for (int n = 0; n < 2; ++n)
                    acc[m][n] = __builtin_amdgcn_mfma_f32_16x16x32_bf16(af[m], bf[n], acc[m][n], 0, 0, 0);
        }
    }

#pragma unroll
    for (int m = 0; m < 2; ++m)
#pragma unroll
        for (int n = 0; n < 2; ++n) {
            int cg = n0 + wc * 32 + n * 16 + (lane & 15);
            float bv = bias[cg];
#pragma unroll
            for (int j = 0; j < 4; ++j) {
                int rg = m0 + wr * 32 + m * 16 + (lane >> 4) * 4 + j;
                float v = acc[m][n][j] + bv;
                if (RELU) v = fmaxf(v, 0.f);
                if (RES) v += res[(size_t)rg * N + cg];
                if (OUTB) outb[(size_t)rg * N + cg] = f2b(v);
                if (OUTF) outf[(size_t)rg * N + cg] = v;
            }
        }
}

// ---------------- Flash attention (ragged, causal), wave-per-q-row ----------------
// Block: 512 threads = 8 waves = 8 consecutive q rows (same sequence: offsets % 64 == 0).
// K/V staged in LDS in 64-key chunks shared by the 8 waves.
__global__ __launch_bounds__(512) void attn_kernel(const u16* __restrict__ qkv,
                                                   const int* __restrict__ amask,
                                                   u16* __restrict__ ctx) {
    __shared__ u16 Ks[64][72];
    __shared__ u16 Vs[64][72];
    __shared__ float q_lds[8][64];
    int t = threadIdx.x, lane = t & 63, w = t >> 6;
    int h = blockIdx.y;
    int r0 = blockIdx.x * 8;
    int b = 0;
#pragma unroll
    for (int i = 0; i < 8; ++i)
        if (r0 >= BOFF[i + 1]) b = i + 1;
    int boff = BOFF[b];
    int r = r0 + w;
    int p = r - boff;          // local query position
    int pmax = r0 + 7 - boff;  // max position among the 8 waves

    // stage q (scaled) -- only read by own wave
    q_lds[w][lane] = b2f(qkv[(size_t)r * QKV3 + h * HD + lane]) * 0.125f;

    float acc = 0.f, mrun = -1e30f, lsum = 0.f;
    const u16* Kg = qkv + EMBED + h * HD;
    const u16* Vg = qkv + 2 * EMBED + h * HD;

    for (int k0 = 0; k0 <= pmax; k0 += 64) {
        int kend = min(64, pmax + 1 - k0);
        __syncthreads();
        {
            int row = t >> 3, cg = t & 7;
            if (row < kend) {
                size_t gro = (size_t)(boff + k0 + row) * QKV3;
                *(uint4*)&Ks[row][cg * 8] = *(const uint4*)&Kg[gro + cg * 8];
                *(uint4*)&Vs[row][cg * 8] = *(const uint4*)&Vg[gro + cg * 8];
            }
        }
        __syncthreads();
        int nkw = p + 1 - k0;
        if (nkw > 0) {
            nkw = min(64, nkw);
            int j = lane;
            float s = -1e30f;
            if (j < nkw && amask[boff + k0 + j] != 0) {
                float d0 = 0.f;
#pragma unroll
                for (int dd = 0; dd < 16; ++dd) {
                    float4 qv = *(const float4*)&q_lds[w][dd * 4];
                    ushort4 kv = *(const ushort4*)&Ks[j][dd * 4];
                    d0 += qv.x * b2f(kv.x) + qv.y * b2f(kv.y) + qv.z * b2f(kv.z) + qv.w * b2f(kv.w);
                }
                s = d0;
            }
            float mchunk = s;
#pragma unroll
            for (int o = 32; o; o >>= 1) mchunk = fmaxf(mchunk, __shfl_xor(mchunk, o));
            float mnew = fmaxf(mrun, mchunk);
            float pj = (j < nkw) ? __expf(s - mnew) : 0.f;
            float psum = pj;
#pragma unroll
            for (int o = 32; o; o >>= 1) psum += __shfl_xor(psum, o);
            float f = __expf(mrun - mnew);
            lsum = lsum * f + psum;
            acc *= f;
            for (int jj = 0; jj < nkw; ++jj) {
                float pjj = __shfl(pj, jj);
                acc += pjj * b2f(Vs[jj][lane]);
            }
            mrun = mnew;
        }
    }
    ctx[(size_t)r * EMBED + h * HD + lane] = f2b(acc / lsum);
}

// ---------------- launch ----------------
extern "C" void kernel_launch(void* const* d_in, const int* in_sizes, int n_in,
                              void* d_out, int out_size, void* d_ws, size_t ws_size,
                              hipStream_t stream) {
    (void)in_sizes; (void)n_in; (void)out_size; (void)ws_size;
    const float* hidden = (const float*)d_in[0];
    const int*   amask  = (const int*)d_in[1];
    const float* in_w   = (const float*)d_in[2];
    const float* in_b   = (const float*)d_in[3];
    const float* out_w  = (const float*)d_in[4];
    const float* out_b  = (const float*)d_in[5];
    const float* ln1g   = (const float*)d_in[6];
    const float* ln1b   = (const float*)d_in[7];
    const float* fc1w   = (const float*)d_in[8];
    const float* fc1b   = (const float*)d_in[9];
    const float* fc2w   = (const float*)d_in[10];
    const float* fc2b   = (const float*)d_in[11];
    const float* ln2g   = (const float*)d_in[12];
    const float* ln2b   = (const float*)d_in[13];
    float* out = (float*)d_out;

    char* ws = (char*)d_ws;
    size_t off = 0;
    auto alloc = [&](size_t bytes) {
        void* p = ws + off;
        off += (bytes + 255) & ~(size_t)255;
        return p;
    };
    u16* w_in_bf  = (u16*)alloc((size_t)QKV3 * EMBED * 2);
    u16* w_out_bf = (u16*)alloc((size_t)EMBED * EMBED * 2);
    u16* w_fc1_bf = (u16*)alloc((size_t)FFN * EMBED * 2);
    u16* w_fc2_bf = (u16*)alloc((size_t)EMBED * FFN * 2);
    u16* xln  = (u16*)alloc((size_t)TOTAL * EMBED * 2);
    u16* qkv  = (u16*)alloc((size_t)TOTAL * QKV3 * 2);
    u16* ctx  = (u16*)alloc((size_t)TOTAL * EMBED * 2);
    float* hmid = (float*)alloc((size_t)TOTAL * EMBED * 4);
    u16* hln  = (u16*)alloc((size_t)TOTAL * EMBED * 2);
    u16* f1o  = (u16*)alloc((size_t)TOTAL * FFN * 2);

    // convert weights to bf16
    {
        int n4;
        n4 = QKV3 * EMBED / 4; cvt_kernel<<<(n4 + 255) / 256, 256, 0, stream>>>(in_w, w_in_bf, n4);
        n4 = EMBED * EMBED / 4; cvt_kernel<<<(n4 + 255) / 256, 256, 0, stream>>>(out_w, w_out_bf, n4);
        n4 = FFN * EMBED / 4; cvt_kernel<<<(n4 + 255) / 256, 256, 0, stream>>>(fc1w, w_fc1_bf, n4);
        n4 = EMBED * FFN / 4; cvt_kernel<<<(n4 + 255) / 256, 256, 0, stream>>>(fc2w, w_fc2_bf, n4);
    }

    // LN1
    ln_kernel<<<TOTAL / 4, 256, 0, stream>>>(hidden, ln1g, ln1b, xln);
    // QKV projection
    gemm_bt<0, 0, 1, 0><<<dim3(QKV3 / 64, TOTAL / 64), 256, 0, stream>>>(
        xln, w_in_bf, in_b, nullptr, qkv, nullptr, TOTAL, QKV3, EMBED);
    // attention
    attn_kernel<<<dim3(TOTAL / 8, NH), 512, 0, stream>>>(qkv, amask, ctx);
    // out_proj + residual -> hmid (fp32)
    gemm_bt<0, 1, 0, 1><<<dim3(EMBED / 64, TOTAL / 64), 256, 0, stream>>>(
        ctx, w_out_bf, out_b, hidden, nullptr, hmid, TOTAL, EMBED, EMBED);
    // LN2
    ln_kernel<<<TOTAL / 4, 256, 0, stream>>>(hmid, ln2g, ln2b, hln);
    // FC1 + ReLU
    gemm_bt<1, 0, 1, 0><<<dim3(FFN / 64, TOTAL / 64), 256, 0, stream>>>(
        hln, w_fc1_bf, fc1b, nullptr, f1o, nullptr, TOTAL, FFN, EMBED);
    // FC2 + residual -> out (fp32)
    gemm_bt<0, 1, 0, 1><<<dim3(EMBED / 64, TOTAL / 64), 256, 0, stream>>>(
        f1o, w_fc2_bf, fc2b, hmid, nullptr, out, TOTAL, EMBED, FFN);
}

// Round 2
// 330.586 us; speedup vs baseline: 2.9075x; 2.9075x over previous
//
#include <hip/hip_runtime.h>
#include <hip/hip_bf16.h>

// Problem constants (baked from reference)
// SEQ_LENS = [1024, 768, 512, 896, 640, 384, 1024, 896], TOTAL=6144
// EMBED=768, HEADS=12, HEAD_DIM=64, FFN=3072
#define TOTAL 6144
#define EMBED 768
#define QKV3  2304
#define FFN   3072
#define NH    12
#define HD    64

typedef unsigned short u16;
typedef unsigned int u32;
typedef float f32x4 __attribute__((ext_vector_type(4)));
typedef __bf16 bf16x8 __attribute__((ext_vector_type(8)));

__device__ __constant__ int BOFF[9] = {0, 1024, 1792, 2304, 3200, 3840, 4224, 5248, 6144};

__device__ __forceinline__ float b2f(u16 h) {
    union { u32 u; float f; } v; v.u = ((u32)h) << 16; return v.f;
}
__device__ __forceinline__ u16 f2b(float f) {
    union { u32 u; float f; } v; v.f = f;
    u32 u = v.u + 0x7fffu + ((v.u >> 16) & 1u);
    return (u16)(u >> 16);
}

// DPP max-reduce across each 16-lane group (quad_perm xor1, xor2, row_ror:4, row_ror:8)
__device__ __forceinline__ float rowmax16(float x) {
    int v;
    v = __builtin_amdgcn_mov_dpp(__float_as_int(x), 0xB1, 0xF, 0xF, true);
    x = fmaxf(x, __int_as_float(v));
    v = __builtin_amdgcn_mov_dpp(__float_as_int(x), 0x4E, 0xF, 0xF, true);
    x = fmaxf(x, __int_as_float(v));
    v = __builtin_amdgcn_mov_dpp(__float_as_int(x), 0x124, 0xF, 0xF, true);
    x = fmaxf(x, __int_as_float(v));
    v = __builtin_amdgcn_mov_dpp(__float_as_int(x), 0x128, 0xF, 0xF, true);
    x = fmaxf(x, __int_as_float(v));
    return x;
}

// ---------------- fp32 -> bf16 convert ----------------
__global__ void cvt_kernel(const float* __restrict__ in, u16* __restrict__ out, int n4) {
    int i = blockIdx.x * blockDim.x + threadIdx.x;
    if (i < n4) {
        float4 v = ((const float4*)in)[i];
        ushort4 o;
        o.x = f2b(v.x); o.y = f2b(v.y); o.z = f2b(v.z); o.w = f2b(v.w);
        ((ushort4*)out)[i] = o;
    }
}

// ---------------- LayerNorm (row of 768), bf16 output ----------------
__global__ __launch_bounds__(256) void ln_kernel(const float* __restrict__ x,
                                                 const float* __restrict__ g,
                                                 const float* __restrict__ b,
                                                 u16* __restrict__ out) {
    int row = blockIdx.x * 4 + (threadIdx.x >> 6);
    int lane = threadIdx.x & 63;
    const float* xr = x + (size_t)row * EMBED;
    float4 v[3];
    float s = 0.f, sq = 0.f;
#pragma unroll
    for (int c = 0; c < 3; ++c) {
        v[c] = *(const float4*)(xr + c * 256 + lane * 4);
        s += v[c].x + v[c].y + v[c].z + v[c].w;
        sq += v[c].x * v[c].x + v[c].y * v[c].y + v[c].z * v[c].z + v[c].w * v[c].w;
    }
#pragma unroll
    for (int o = 32; o; o >>= 1) {
        s += __shfl_xor(s, o);
        sq += __shfl_xor(sq, o);
    }
    float mu = s * (1.f / 768.f);
    float var = sq * (1.f / 768.f) - mu * mu;
    float rs = rsqrtf(var + 1e-5f);
    u16* orow = out + (size_t)row * EMBED;
#pragma unroll
    for (int c = 0; c < 3; ++c) {
        int col = c * 256 + lane * 4;
        float4 gg = *(const float4*)(g + col);
        float4 bb = *(const float4*)(b + col);
        ushort4 o;
        o.x = f2b((v[c].x - mu) * rs * gg.x + bb.x);
        o.y = f2b((v[c].y - mu) * rs * gg.y + bb.y);
        o.z = f2b((v[c].z - mu) * rs * gg.z + bb.z);
        o.w = f2b((v[c].w - mu) * rs * gg.w + bb.w);
        *(ushort4*)(orow + col) = o;
    }
}

// ---------------- GEMM: C[M,N] = A[M,K] @ B[N,K]^T + bias (+relu) (+res) ----------------
template <int RELU, int RES, int OUTB, int OUTF>
__global__ __launch_bounds__(256) void gemm_bt(const u16* __restrict__ A,
                                               const u16* __restrict__ B,
                                               const float* __restrict__ bias,
                                               const float* __restrict__ res,
                                               u16* __restrict__ outb,
                                               float* __restrict__ outf,
                                               int M, int N, int K) {
    __shared__ u16 As[64][72];
    __shared__ u16 Bs[64][72];
    int t = threadIdx.x;
    int lane = t & 63, w = t >> 6;
    int wr = w >> 1, wc = w & 1;
    int m0 = blockIdx.y * 64, n0 = blockIdx.x * 64;

    f32x4 acc[2][2];
#pragma unroll
    for (int m = 0; m < 2; ++m)
#pragma unroll
        for (int n = 0; n < 2; ++n) acc[m][n] = (f32x4)0.f;

    for (int k0 = 0; k0 < K; k0 += 64) {
        __syncthreads();
#pragma unroll
        for (int l = 0; l < 2; ++l) {
            int idx = l * 256 + t;
            int row = idx >> 3, cg = idx & 7;
            *(uint4*)&As[row][cg * 8] = *(const uint4*)&A[(size_t)(m0 + row) * K + k0 + cg * 8];
            *(uint4*)&Bs[row][cg * 8] = *(const uint4*)&B[(size_t)(n0 + row) * K + k0 + cg * 8];
        }
        __syncthreads();
#pragma unroll
        for (int kk = 0; kk < 2; ++kk) {
            int kcol = kk * 32 + (lane >> 4) * 8;
            bf16x8 af[2], bf[2];
#pragma unroll
            for (int m = 0; m < 2; ++m)
                af[m] = *(const bf16x8*)&As[wr * 32 + m * 16 + (lane & 15)][kcol];
#pragma unroll
            for (int n = 0; n < 2; ++n)
                bf[n] = *(const bf16x8*)&Bs[wc * 32 + n * 16 + (lane & 15)][kcol];
#pragma unroll
            for (int m = 0; m < 2; ++m)
#pragma unroll
                for (int n = 0; n < 2; ++n)
                    acc[m][n] = __builtin_amdgcn_mfma_f32_16x16x32_bf16(af[m], bf[n], acc[m][n], 0, 0, 0);
        }
    }

#pragma unroll
    for (int m = 0; m < 2; ++m)
#pragma unroll
        for (int n = 0; n < 2; ++n) {
            int cg = n0 + wc * 32 + n * 16 + (lane & 15);
            float bv = bias[cg];
#pragma unroll
            for (int j = 0; j < 4; ++j) {
                int rg = m0 + wr * 32 + m * 16 + (lane >> 4) * 4 + j;
                float v = acc[m][n][j] + bv;
                if (RELU) v = fmaxf(v, 0.f);
                if (RES) v += res[(size_t)rg * N + cg];
                if (OUTB) outb[(size_t)rg * N + cg] = f2b(v);
                if (OUTF) outf[(size_t)rg * N + cg] = v;
            }
        }
}

// ---------------- V transpose: qkv V-section [row][dim] -> vT [dim][row] ----------------
// 64x64 tiles via swizzled LDS (conflict-free both phases), coalesced global both sides.
__global__ __launch_bounds__(256) void vtrans_kernel(const u16* __restrict__ qkv,
                                                     u16* __restrict__ vT) {
    __shared__ u16 T[64][64];
    int t = threadIdx.x;
    int r0 = blockIdx.x * 64;
    int d0 = blockIdx.y * 64;
#pragma unroll
    for (int s = 0; s < 2; ++s) {
        int idx = s * 256 + t;
        int r = idx >> 3, cg = idx & 7;
        uint4 v = *(const uint4*)&qkv[(size_t)(r0 + r) * QKV3 + 2 * EMBED + d0 + cg * 8];
        int sw = (((r & 7) ^ ((r >> 3) & 7)) << 3);
        *(uint4*)&T[r][(cg * 8) ^ sw] = v;
    }
    __syncthreads();
#pragma unroll
    for (int s = 0; s < 2; ++s) {
        int idx = s * 256 + t;
        int gd = idx >> 3, rc = idx & 7;
        u16 tmp[8];
#pragma unroll
        for (int j = 0; j < 8; ++j) {
            int row = rc * 8 + j;
            int sw = (((row & 7) ^ ((row >> 3) & 7)) << 3);
            tmp[j] = T[row][gd ^ sw];
        }
        *(uint4*)&vT[(size_t)(d0 + gd) * TOTAL + r0 + rc * 8] = *(uint4*)tmp;
    }
}

// ---------------- MFMA flash attention (ragged, causal) ----------------
// Block = 4 waves x 32 q-rows = 128-row q-tile for one head. KV chunks of 64 staged in LDS.
__global__ __launch_bounds__(256) void attn_mfma(const u16* __restrict__ qkv,
                                                 const u16* __restrict__ vT,
                                                 const int* __restrict__ amask,
                                                 u16* __restrict__ ctx) {
    __shared__ u16 Ks[64][72];
    __shared__ u16 Vt[64][72];   // [dim][key]
    __shared__ u16 Pl[4][32][72];
    int t = threadIdx.x, l = t & 63, w = t >> 6;
    int Q = l >> 4, c = l & 15;
    int h = blockIdx.y;
    int qt = gridDim.x - 1 - blockIdx.x;  // heavy tiles first
    int r0 = qt * 128;
    int b = 0;
#pragma unroll
    for (int i = 0; i < 8; ++i)
        if (r0 >= BOFF[i + 1]) b = i + 1;
    int boff = BOFF[b];
    int p0 = r0 - boff;
    int nk = p0 + 128;
    int pw = p0 + w * 32;
    int qrow = r0 + w * 32;

    // Q fragments (A-frag: row = c, k = Q*8.. ; two 32-wide k-steps)
    bf16x8 qa[2][2];
#pragma unroll
    for (int m = 0; m < 2; ++m)
#pragma unroll
        for (int ks = 0; ks < 2; ++ks)
            qa[m][ks] = *(const bf16x8*)&qkv[(size_t)(qrow + m * 16 + c) * QKV3 + h * HD + ks * 32 + Q * 8];

    bf16x8 vones;
#pragma unroll
    for (int j = 0; j < 8; ++j) vones[j] = (__bf16)1.0f;

    f32x4 oacc[2][4], lacc[2];
    float mrun[2][4];
#pragma unroll
    for (int m = 0; m < 2; ++m) {
        lacc[m] = (f32x4)0.f;
#pragma unroll
        for (int nt = 0; nt < 4; ++nt) oacc[m][nt] = (f32x4)0.f;
#pragma unroll
        for (int r = 0; r < 4; ++r) mrun[m][r] = -1e30f;
    }

    for (int k0 = 0; k0 < nk; k0 += 64) {
        __syncthreads();
#pragma unroll
        for (int s = 0; s < 2; ++s) {
            int idx = s * 256 + t;
            int row = idx >> 3, cg = idx & 7;
            *(uint4*)&Ks[row][cg * 8] =
                *(const uint4*)&qkv[(size_t)(boff + k0 + row) * QKV3 + EMBED + h * HD + cg * 8];
            *(uint4*)&Vt[row][cg * 8] =
                *(const uint4*)&vT[(size_t)(h * HD + row) * TOTAL + boff + k0 + cg * 8];
        }
        __syncthreads();
        if (k0 > pw + 31) continue;  // this wave's rows need no keys here

        // QK^T
        f32x4 sacc[2][4];
#pragma unroll
        for (int m = 0; m < 2; ++m)
#pragma unroll
            for (int nt = 0; nt < 4; ++nt) sacc[m][nt] = (f32x4)0.f;
#pragma unroll
        for (int ks = 0; ks < 2; ++ks) {
            bf16x8 kb[4];
#pragma unroll
            for (int nt = 0; nt < 4; ++nt)
                kb[nt] = *(const bf16x8*)&Ks[nt * 16 + c][ks * 32 + Q * 8];
#pragma unroll
            for (int m = 0; m < 2; ++m)
#pragma unroll
                for (int nt = 0; nt < 4; ++nt)
                    sacc[m][nt] = __builtin_amdgcn_mfma_f32_16x16x32_bf16(qa[m][ks], kb[nt], sacc[m][nt], 0, 0, 0);
        }

        // scale + masks
        int am[4];
#pragma unroll
        for (int nt = 0; nt < 4; ++nt) am[nt] = amask[boff + k0 + nt * 16 + c];
#pragma unroll
        for (int m = 0; m < 2; ++m)
#pragma unroll
            for (int nt = 0; nt < 4; ++nt) {
                int kpos = k0 + nt * 16 + c;
                float madd = am[nt] ? 0.f : -1e30f;
#pragma unroll
                for (int r = 0; r < 4; ++r) {
                    float s = fmaf(sacc[m][nt][r], 0.125f, madd);
                    int qp = pw + m * 16 + 4 * Q + r;
                    sacc[m][nt][r] = (kpos <= qp) ? s : -1e30f;
                }
            }

        // row max (per 16-lane group) + deferred rescale
        float mx[2][4];
        int small = 1;
#pragma unroll
        for (int m = 0; m < 2; ++m)
#pragma unroll
            for (int r = 0; r < 4; ++r) {
                float v = fmaxf(fmaxf(sacc[m][0][r], sacc[m][1][r]),
                                fmaxf(sacc[m][2][r], sacc[m][3][r]));
                v = rowmax16(v);
                mx[m][r] = v;
                small &= (v <= mrun[m][r]) ? 1 : 0;
            }
        if (!__all(small)) {
#pragma unroll
            for (int m = 0; m < 2; ++m)
#pragma unroll
                for (int r = 0; r < 4; ++r) {
                    float mn = fmaxf(mrun[m][r], mx[m][r]);
                    float f = __expf(mrun[m][r] - mn);
                    mrun[m][r] = mn;
                    lacc[m][r] *= f;
#pragma unroll
                    for (int nt = 0; nt < 4; ++nt) oacc[m][nt][r] *= f;
                }
        }

        // P = exp(s - m), to per-wave LDS (bf16)
#pragma unroll
        for (int m = 0; m < 2; ++m)
#pragma unroll
            for (int nt = 0; nt < 4; ++nt)
#pragma unroll
                for (int r = 0; r < 4; ++r) {
                    float p = __expf(sacc[m][nt][r] - mrun[m][r]);
                    Pl[w][m * 16 + 4 * Q + r][nt * 16 + c] = f2b(p);
                }

        // PV + row-sum (via all-ones B fragment)
#pragma unroll
        for (int ks = 0; ks < 2; ++ks) {
            bf16x8 pa[2], vb[4];
#pragma unroll
            for (int m = 0; m < 2; ++m)
                pa[m] = *(const bf16x8*)&Pl[w][m * 16 + c][ks * 32 + Q * 8];
#pragma unroll
            for (int nt = 0; nt < 4; ++nt)
                vb[nt] = *(const bf16x8*)&Vt[nt * 16 + c][ks * 32 + Q * 8];
#pragma unroll
            for (int m = 0; m < 2; ++m) {
                lacc[m] = __builtin_amdgcn_mfma_f32_16x16x32_bf16(pa[m], vones, lacc[m], 0, 0, 0);
#pragma unroll
                for (int nt = 0; nt < 4; ++nt)
                    oacc[m][nt] = __builtin_amdgcn_mfma_f32_16x16x32_bf16(pa[m], vb[nt], oacc[m][nt], 0, 0, 0);
            }
        }
    }

    // epilogue: divide by row-sums, write ctx
#pragma unroll
    for (int m = 0; m < 2; ++m)
#pragma unroll
        for (int r = 0; r < 4; ++r) {
            float inv = 1.0f / lacc[m][r];
#pragma unroll
            for (int nt = 0; nt < 4; ++nt)
                ctx[(size_t)(qrow + m * 16 + 4 * Q + r) * EMBED + h * HD + nt * 16 + c] =
                    f2b(oacc[m][nt][r] * inv);
        }
}

// ---------------- launch ----------------
extern "C" void kernel_launch(void* const* d_in, const int* in_sizes, int n_in,
                              void* d_out, int out_size, void* d_ws, size_t ws_size,
                              hipStream_t stream) {
    (void)in_sizes; (void)n_in; (void)out_size; (void)ws_size;
    const float* hidden = (const float*)d_in[0];
    const int*   amask  = (const int*)d_in[1];
    const float* in_w   = (const float*)d_in[2];
    const float* in_b   = (const float*)d_in[3];
    const float* out_w  = (const float*)d_in[4];
    const float* out_b  = (const float*)d_in[5];
    const float* ln1g   = (const float*)d_in[6];
    const float* ln1b   = (const float*)d_in[7];
    const float* fc1w   = (const float*)d_in[8];
    const float* fc1b   = (const float*)d_in[9];
    const float* fc2w   = (const float*)d_in[10];
    const float* fc2b   = (const float*)d_in[11];
    const float* ln2g   = (const float*)d_in[12];
    const float* ln2b   = (const float*)d_in[13];
    float* out = (float*)d_out;

    char* ws = (char*)d_ws;
    size_t off = 0;
    auto alloc = [&](size_t bytes) {
        void* p = ws + off;
        off += (bytes + 255) & ~(size_t)255;
        return p;
    };
    u16* w_in_bf  = (u16*)alloc((size_t)QKV3 * EMBED * 2);
    u16* w_out_bf = (u16*)alloc((size_t)EMBED * EMBED * 2);
    u16* w_fc1_bf = (u16*)alloc((size_t)FFN * EMBED * 2);
    u16* w_fc2_bf = (u16*)alloc((size_t)EMBED * FFN * 2);
    u16* xln  = (u16*)alloc((size_t)TOTAL * EMBED * 2);
    u16* qkv  = (u16*)alloc((size_t)TOTAL * QKV3 * 2);
    u16* ctx  = (u16*)alloc((size_t)TOTAL * EMBED * 2);
    float* hmid = (float*)alloc((size_t)TOTAL * EMBED * 4);
    u16* hln  = (u16*)alloc((size_t)TOTAL * EMBED * 2);
    u16* f1o  = (u16*)alloc((size_t)TOTAL * FFN * 2);
    u16* vT   = xln;  // xln is dead after the QKV GEMM; reuse as V^T [768][6144]

    // convert weights to bf16
    {
        int n4;
        n4 = QKV3 * EMBED / 4; cvt_kernel<<<(n4 + 255) / 256, 256, 0, stream>>>(in_w, w_in_bf, n4);
        n4 = EMBED * EMBED / 4; cvt_kernel<<<(n4 + 255) / 256, 256, 0, stream>>>(out_w, w_out_bf, n4);
        n4 = FFN * EMBED / 4; cvt_kernel<<<(n4 + 255) / 256, 256, 0, stream>>>(fc1w, w_fc1_bf, n4);
        n4 = EMBED * FFN / 4; cvt_kernel<<<(n4 + 255) / 256, 256, 0, stream>>>(fc2w, w_fc2_bf, n4);
    }

    // LN1
    ln_kernel<<<TOTAL / 4, 256, 0, stream>>>(hidden, ln1g, ln1b, xln);
    // QKV projection
    gemm_bt<0, 0, 1, 0><<<dim3(QKV3 / 64, TOTAL / 64), 256, 0, stream>>>(
        xln, w_in_bf, in_b, nullptr, qkv, nullptr, TOTAL, QKV3, EMBED);
    // V transpose (xln is now dead; vT aliases it)
    vtrans_kernel<<<dim3(TOTAL / 64, EMBED / 64), 256, 0, stream>>>(qkv, vT);
    // attention
    attn_mfma<<<dim3(TOTAL / 128, NH), 256, 0, stream>>>(qkv, vT, amask, ctx);
    // out_proj + residual -> hmid (fp32)
    gemm_bt<0, 1, 0, 1><<<dim3(EMBED / 64, TOTAL / 64), 256, 0, stream>>>(
        ctx, w_out_bf, out_b, hidden, nullptr, hmid, TOTAL, EMBED, EMBED);
    // LN2
    ln_kernel<<<TOTAL / 4, 256, 0, stream>>>(hmid, ln2g, ln2b, hln);
    // FC1 + ReLU
    gemm_bt<1, 0, 1, 0><<<dim3(FFN / 64, TOTAL / 64), 256, 0, stream>>>(
        hln, w_fc1_bf, fc1b, nullptr, f1o, nullptr, TOTAL, FFN, EMBED);
    // FC2 + residual -> out (fp32)
    gemm_bt<0, 1, 0, 1><<<dim3(EMBED / 64, TOTAL / 64), 256, 0, stream>>>(
        f1o, w_fc2_bf, fc2b, hmid, nullptr, out, TOTAL, EMBED, FFN);
}